// Round 10
// baseline (311.885 us; speedup 1.0000x reference)
//
#include <hip/hip_runtime.h>

// Triangle multiplication (outgoing), B=1 N=512 CZ=128 C=16, f32 I/O.
// K0 pack weights f32->bf16 -> K1 proj GEMM (R7-best: 2048 blocks x 128 rows,
// W in LDS, direct-x A-frags, LDS-transpose epilogue) -> K2 per-channel 512^3
// bf16 GEMMs (v6: 128x64 tiles, 512 blocks = 2/CU co-resident, fused
// scatter-transpose B staging + T14 async prefetch) -> K3 LN+matvec+gate.

#define NN 512
#define PP (NN*NN)        // 262144
#define CZD 128
#define CD 16
#define LN_EPS 1e-5f

typedef unsigned short u16;
typedef __bf16 bf16x8 __attribute__((ext_vector_type(8)));
typedef float  f32x4  __attribute__((ext_vector_type(4)));

// ws layout (bytes)
#define OFF_A  0u           // a planes: 16 x P x bf16 = 8 MB
#define OFF_B  8388608u     // b planes: 8 MB
#define OFF_Z  16777216u    // z: 16 x P x f32 = 16 MB
#define OFF_G  33554432u    // g: P x 128 x bf16 = 64 MB
#define OFF_WT 100663296u   // packed Wt[192][128] bf16
#define OFF_BC 100712448u   // bias cat [192] f32

__device__ __forceinline__ float bf2f(u16 u) {
    union { unsigned int i; float f; } v; v.i = ((unsigned int)u) << 16; return v.f;
}
// Native cast: compiler forms v_cvt_pk_bf16_f32 (RNE) from adjacent scalar casts.
__device__ __forceinline__ u16 f2bf(float f) {
    union { __bf16 b; u16 u; } v; v.b = (__bf16)f; return v.u;
}
__device__ __forceinline__ float sigmoidf(float x) { return 1.0f / (1.0f + __expf(-x)); }

// proj LDS addressing, 256B row stride. ROT-16 swizzle: granule' = (granule+row)&15.
__device__ __forceinline__ int swz(int row, int bytecol) {
    return row * 256 + ((((bytecol >> 4) + row) & 15) << 4) + (bytecol & 15);
}

// ---------------- K0: pack Wt[192][128] bf16 (row n holds W[:,n]) + bias[192] f32
__global__ void pack_w(const float* __restrict__ Wa1, const float* __restrict__ Wa2,
                       const float* __restrict__ Wb1, const float* __restrict__ Wb2,
                       const float* __restrict__ Wg,
                       const float* __restrict__ ba1, const float* __restrict__ ba2,
                       const float* __restrict__ bb1, const float* __restrict__ bb2,
                       const float* __restrict__ bg,
                       u16* __restrict__ wt, float* __restrict__ bc) {
    int idx = blockIdx.x * 256 + threadIdx.x;           // 0..24575
    int n = idx >> 7, k = idx & 127;
    float v;
    if      (n < 16) v = Wa1[k * CD + n];
    else if (n < 32) v = Wa2[k * CD + (n - 16)];
    else if (n < 48) v = Wb1[k * CD + (n - 32)];
    else if (n < 64) v = Wb2[k * CD + (n - 48)];
    else             v = Wg [k * CZD + (n - 64)];
    wt[n * CZD + k] = f2bf(v);
    if (idx < 192) {
        float b;
        if      (idx < 16) b = ba1[idx];
        else if (idx < 32) b = ba2[idx - 16];
        else if (idx < 48) b = bb1[idx - 32];
        else if (idx < 64) b = bb2[idx - 48];
        else               b = bg [idx - 64];
        bc[idx] = b;
    }
}

// ---------------- K1: X[P,128] @ Wcat[128,192] with fused sigmoid epilogue.
// R7-best config (frozen): 512 thr, 128 rows/block (2048 blocks), W in LDS 48KB,
// direct-x A-frags, LDS-transpose epilogue.
__global__ __launch_bounds__(512, 4) void proj_kernel(const float* __restrict__ x,
                                                      const u16* __restrict__ wt,
                                                      const float* __restrict__ bc,
                                                      u16* __restrict__ a_ws, u16* __restrict__ b_ws,
                                                      u16* __restrict__ g_ws) {
    __shared__ __align__(16) char lds[49152];           // W: 192 rows x 256B
    char* Wl = lds;
    char* aT = lds;                                     // epilogue reuse: 16 rows x 256B
    char* bT = lds + 4096;                              // 16 rows x 256B
    char* gT = lds + 8192;                              // 128 rows x 256B
    const int t = threadIdx.x;
    const int wv = t >> 6, lane = t & 63, l16 = lane & 15, quad = lane >> 4;
    const long pos0 = (long)blockIdx.x * 128;

    // issue A-fragment global loads first (8 x float4, in flight during W stage)
    const float* xrow = x + (pos0 + wv * 16 + l16) * CZD + quad * 8;
    float4 xa[4][2];
#pragma unroll
    for (int ks = 0; ks < 4; ++ks) {
        xa[ks][0] = *reinterpret_cast<const float4*>(xrow + ks * 32);
        xa[ks][1] = *reinterpret_cast<const float4*>(xrow + ks * 32 + 4);
    }

    // stage W: 192 rows x 16 granules(16B) = 3072 chunks, 6/thread
#pragma unroll
    for (int i = 0; i < 6; ++i) {
        int c = t + 512 * i;
        int n = c >> 4, g = c & 15;
        uint4 v = *reinterpret_cast<const uint4*>(wt + n * CZD + g * 8);
        *reinterpret_cast<uint4*>(Wl + swz(n, g * 16)) = v;
    }

    // convert A fragments f32 -> bf16 in registers
    bf16x8 af[4];
#pragma unroll
    for (int ks = 0; ks < 4; ++ks) {
        union { u16 s[8]; bf16x8 v; } tb;
        tb.s[0] = f2bf(xa[ks][0].x); tb.s[1] = f2bf(xa[ks][0].y);
        tb.s[2] = f2bf(xa[ks][0].z); tb.s[3] = f2bf(xa[ks][0].w);
        tb.s[4] = f2bf(xa[ks][1].x); tb.s[5] = f2bf(xa[ks][1].y);
        tb.s[6] = f2bf(xa[ks][1].z); tb.s[7] = f2bf(xa[ks][1].w);
        af[ks] = tb.v;
    }
    __syncthreads();

    f32x4 acc[12];
#pragma unroll
    for (int ct = 0; ct < 12; ++ct) acc[ct] = (f32x4){0.f, 0.f, 0.f, 0.f};
#pragma unroll
    for (int ks = 0; ks < 4; ++ks)
#pragma unroll
        for (int ct = 0; ct < 12; ++ct) {
            bf16x8 wb = *reinterpret_cast<const bf16x8*>(Wl + swz(ct * 16 + l16, ks * 64 + quad * 16));
            acc[ct] = __builtin_amdgcn_mfma_f32_16x16x32_bf16(af[ks], wb, acc[ct], 0, 0, 0);
        }
    __syncthreads();                                    // all waves done reading Wl

    // epilogue: sigmoid + transpose into LDS (aliases Wl region)
    {
        const float ba1 = bc[l16], ba2 = bc[16 + l16], bb1 = bc[32 + l16], bb2 = bc[48 + l16];
        u16 av[4], bv[4];
#pragma unroll
        for (int r = 0; r < 4; ++r) {
            av[r] = f2bf(sigmoidf((acc[0][r] + ba1) * (acc[1][r] + ba2)));
            bv[r] = f2bf(sigmoidf((acc[2][r] + bb1) * (acc[3][r] + bb2)));
        }
        *reinterpret_cast<uint2*>(aT + swz(l16, wv * 32 + quad * 8)) = *reinterpret_cast<const uint2*>(av);
        *reinterpret_cast<uint2*>(bT + swz(l16, wv * 32 + quad * 8)) = *reinterpret_cast<const uint2*>(bv);
#pragma unroll
        for (int ct = 0; ct < 8; ++ct) {
            const float bgv = bc[64 + ct * 16 + l16];
#pragma unroll
            for (int r = 0; r < 4; ++r) {
                int pos = wv * 16 + quad * 4 + r;
                *reinterpret_cast<u16*>(gT + swz(pos, ct * 32 + l16 * 2)) =
                    f2bf(sigmoidf(acc[4 + ct][r] + bgv));
            }
        }
    }
    __syncthreads();

    // coalesced write-out: aT/bT 4KB each (16 ch x 128 pos u16), gT 32KB
    if (t < 256) {
        int ch = t >> 4, i = t & 15;
        uint4 v = *reinterpret_cast<const uint4*>(aT + swz(ch, i * 16));
        *reinterpret_cast<uint4*>(a_ws + (long)ch * PP + pos0 + i * 8) = v;
    } else {
        int u = t - 256;
        int ch = u >> 4, i = u & 15;
        uint4 v = *reinterpret_cast<const uint4*>(bT + swz(ch, i * 16));
        *reinterpret_cast<uint4*>(b_ws + (long)ch * PP + pos0 + i * 8) = v;
    }
#pragma unroll
    for (int i = 0; i < 4; ++i) {
        int c = t + 512 * i;                             // 2048 = 128 pos x 16 granules
        int pos = c >> 4, g = c & 15;
        uint4 v = *reinterpret_cast<const uint4*>(gT + swz(pos, g * 16));
        *reinterpret_cast<uint4*>(g_ws + (pos0 + pos) * CZD + g * 8) = v;
    }
}

// ---------------- K2: per-channel Z_c = A_c @ B_c (512x512x512).
// v6: 128x64 tiles -> 512 blocks = 2 blocks/CU CO-RESIDENT (was 1/CU single
// generation: every barrier stalled the whole CU; now the other block fills the
// stall). LDS 24KB/block. A traffic doubles (L2-hot, ~2us) -- the bet is barrier
// overlap wins. B staging: threads<256 load k-pairs, packed b32 scatter (<=2-way,
// free). T14 prefetch kept for A (all threads) and B (t<256).
__global__ __launch_bounds__(512) void tri_kernel(const u16* __restrict__ a_ws,
                                                  const u16* __restrict__ b_ws,
                                                  float* __restrict__ z_ws) {
    __shared__ __align__(16) char Alds[16384];          // A: 128 rows x 128B, granule-swizzled
    __shared__ __align__(16) char Btl [8192];           // B^T: 64 j-rows x 128B (64 k), swizzled
    const int t = threadIdx.x;
    const int wv = t >> 6, lane = t & 63, l16 = lane & 15, quad = lane >> 4;
    const int wr = wv >> 2, wc = wv & 3;                // wave grid 2(x64 i) x 4(x16 j)
    const int c = blockIdx.y;
    const int i0 = (blockIdx.x >> 3) * 128, j0 = (blockIdx.x & 7) * 64;
    const u16* Ap = a_ws + (long)c * PP;
    const u16* Bp = b_ws + (long)c * PP;

    // fixed per-thread staging coordinates
    const int ar0 = t >> 3,          ako0 = (t & 7) * 8;            // A chunk 0 (rows 0..63)
    const int ar1 = (t + 512) >> 3,  ako1 = ((t + 512) & 7) * 8;    // A chunk 1 (rows 64..127)
    const int bk  = (t >> 3) * 2,    bjo  = (t & 7) * 8;            // B k-pair (t<256)
    const int bkg = bk >> 3,         bkl  = (bk & 7) * 2;

    f32x4 acc[4];
#pragma unroll
    for (int m = 0; m < 4; ++m) acc[m] = (f32x4){0.f, 0.f, 0.f, 0.f};

    // prologue: issue k-step 0 loads
    uint4 aR0 = *reinterpret_cast<const uint4*>(Ap + (long)(i0 + ar0) * NN + ako0);
    uint4 aR1 = *reinterpret_cast<const uint4*>(Ap + (long)(i0 + ar1) * NN + ako1);
    uint4 bR0 = {0,0,0,0}, bR1 = {0,0,0,0};
    if (t < 256) {
        bR0 = *reinterpret_cast<const uint4*>(Bp + (long)(bk)     * NN + j0 + bjo);
        bR1 = *reinterpret_cast<const uint4*>(Bp + (long)(bk + 1) * NN + j0 + bjo);
    }

    for (int s = 0; s < 8; ++s) {
        // ds_write staged regs (waits on the in-flight loads)
        *reinterpret_cast<uint4*>(Alds + ar0 * 128 + ((ako0 * 2) ^ ((ar0 & 7) << 4))) = aR0;
        *reinterpret_cast<uint4*>(Alds + ar1 * 128 + ((ako1 * 2) ^ ((ar1 & 7) << 4))) = aR1;
        if (t < 256) {
            union { uint4 v; u16 sh[8]; } t0, t1;
            t0.v = bR0; t1.v = bR1;
#pragma unroll
            for (int jj = 0; jj < 8; ++jj) {
                int j = bjo + jj;
                int gran = ((bkg ^ (j & 7)) + (j >> 3)) & 7;
                unsigned int pk = (unsigned int)t0.sh[jj] | ((unsigned int)t1.sh[jj] << 16);
                *reinterpret_cast<unsigned int*>(Btl + j * 128 + gran * 16 + bkl) = pk;
            }
        }
        __syncthreads();

        // issue NEXT step's loads now -- latency hides under this step's compute
        if (s < 7) {
            const int kn = (s + 1) * 64;
            aR0 = *reinterpret_cast<const uint4*>(Ap + (long)(i0 + ar0) * NN + kn + ako0);
            aR1 = *reinterpret_cast<const uint4*>(Ap + (long)(i0 + ar1) * NN + kn + ako1);
            if (t < 256) {
                bR0 = *reinterpret_cast<const uint4*>(Bp + (long)(kn + bk)     * NN + j0 + bjo);
                bR1 = *reinterpret_cast<const uint4*>(Bp + (long)(kn + bk + 1) * NN + j0 + bjo);
            }
        }

#pragma unroll
        for (int ks = 0; ks < 2; ++ks) {                 // two K=32 halves
            bf16x8 af[4];
#pragma unroll
            for (int m = 0; m < 4; ++m) {
                int row = wr * 64 + m * 16 + l16;
                af[m] = *reinterpret_cast<const bf16x8*>(
                    Alds + row * 128 + ((ks * 64 + quad * 16) ^ ((row & 7) << 4)));
            }
            {
                int jrow = wc * 16 + l16;                // 64 j-rows
                int gran = (((ks * 4 + quad) ^ (jrow & 7)) + (jrow >> 3)) & 7;
                bf16x8 bf = *reinterpret_cast<const bf16x8*>(Btl + jrow * 128 + gran * 16);
#pragma unroll
                for (int m = 0; m < 4; ++m)
                    acc[m] = __builtin_amdgcn_mfma_f32_16x16x32_bf16(af[m], bf, acc[m], 0, 0, 0);
            }
        }
        __syncthreads();                                 // LDS free for next ds_write
    }
    float* Zp = z_ws + (long)c * PP;
#pragma unroll
    for (int m = 0; m < 4; ++m)
#pragma unroll
        for (int r = 0; r < 4; ++r)
            Zp[(long)(i0 + wr * 64 + m * 16 + quad * 4 + r) * NN + j0 + wc * 16 + l16] = acc[m][r];
}

// ---------------- K3: out[pos][cz] = g[pos][cz] * (LN(z[pos][:]) @ Wz + bz)[cz], f32 out
// (frozen) 1024 blocks x 2 tiles of 128 pos; z for both tiles loaded up-front.
__global__ __launch_bounds__(512) void out_kernel(const float* __restrict__ z_ws,
                                                  const u16* __restrict__ g_ws,
                                                  const float* __restrict__ Wz, const float* __restrict__ bz,
                                                  const float* __restrict__ lng, const float* __restrict__ lnb,
                                                  float* __restrict__ out) {
    __shared__ __align__(16) float zt[16][128];
    __shared__ __align__(16) float nl[128][20];          // 80B stride: 16B-aligned rows
    __shared__ __align__(16) float wzs[16][128];
    __shared__ float bzl[128];
    __shared__ float lg[16], lb[16];
    const int t = threadIdx.x;
    const long tbase = (long)blockIdx.x * 256;

    // up-front z loads for BOTH tiles (in flight during Wz stage + LN)
    const int zch = t >> 5, zoff = (t & 31) * 4;
    const float* zp = z_ws + (long)zch * PP + tbase + zoff;
    const float4 zv0 = *reinterpret_cast<const float4*>(zp);
    const float4 zv1 = *reinterpret_cast<const float4*>(zp + 128);

    {   // stage Wz: 2048 floats, 1 float4/thread
        int idx = t * 4;
        const float4 v = *reinterpret_cast<const float4*>(Wz + idx);
        *reinterpret_cast<float4*>(&wzs[idx >> 7][idx & 127]) = v;
    }
    if (t < 128)      bzl[t] = bz[t];
    else if (t < 144) lg[t - 128] = lng[t - 128];
    else if (t < 160) lb[t - 144] = lnb[t - 144];
    *reinterpret_cast<float4*>(&zt[zch][zoff]) = zv0;
    __syncthreads();

    // per-thread weight regs for the matvec (cz pair)
    const int czp = (t & 63) * 2, pg = t >> 6;
    float wzr[32];
#pragma unroll
    for (int c0 = 0; c0 < 16; ++c0) {
        wzr[2 * c0]     = wzs[c0][czp];
        wzr[2 * c0 + 1] = wzs[c0][czp + 1];
    }
    const float bz0 = bzl[czp], bz1 = bzl[czp + 1];
    const unsigned int* gp = reinterpret_cast<const unsigned int*>(g_ws);

#pragma unroll
    for (int it = 0; it < 2; ++it) {
        const long pos0 = tbase + it * 128;
        {   // LN over 16 channels; thread (p = t&127, cgr = t>>7) normalizes 4 channels
            int p = t & 127, cgr = t >> 7;
            float m = 0.f;
#pragma unroll
            for (int c0 = 0; c0 < 16; ++c0) m += zt[c0][p];
            m *= (1.f / 16.f);
            float v = 0.f;
#pragma unroll
            for (int c0 = 0; c0 < 16; ++c0) { float d = zt[c0][p] - m; v += d * d; }
            v *= (1.f / 16.f);
            float s = rsqrtf(v + LN_EPS);
#pragma unroll
            for (int cc = 0; cc < 4; ++cc) {
                int c0 = cgr * 4 + cc;
                nl[p][c0] = (zt[c0][p] - m) * s * lg[c0] + lb[c0];
            }
        }
        __syncthreads();                                 // nl ready; zt consumed
        if (it == 0)                                     // refill zt for tile 1 during matvec
            *reinterpret_cast<float4*>(&zt[zch][zoff]) = zv1;

        // matvec+gate: thread owns cz pair x 16 positions
#pragma unroll
        for (int pp2 = 0; pp2 < 16; ++pp2) {
            int p = pg * 16 + pp2;                       // wave-uniform -> nl reads broadcast
            const float4* np = reinterpret_cast<const float4*>(&nl[p][0]);
            float y0 = bz0, y1 = bz1;
#pragma unroll
            for (int c4 = 0; c4 < 4; ++c4) {
                float4 nv = np[c4];
                y0 += nv.x * wzr[(c4 * 4 + 0) * 2] + nv.y * wzr[(c4 * 4 + 1) * 2] +
                      nv.z * wzr[(c4 * 4 + 2) * 2] + nv.w * wzr[(c4 * 4 + 3) * 2];
                y1 += nv.x * wzr[(c4 * 4 + 0) * 2 + 1] + nv.y * wzr[(c4 * 4 + 1) * 2 + 1] +
                      nv.z * wzr[(c4 * 4 + 2) * 2 + 1] + nv.w * wzr[(c4 * 4 + 3) * 2 + 1];
            }
            long o = (pos0 + p) * CZD + czp;
            unsigned int gg = gp[o >> 1];                // o even: czp even, CZD even
            float g0 = bf2f((u16)(gg & 0xffffu));
            float g1 = bf2f((u16)(gg >> 16));
            float2 res; res.x = g0 * y0; res.y = g1 * y1;
            *reinterpret_cast<float2*>(out + o) = res;
        }
        __syncthreads();                                 // zt(1) visible, nl free
    }
}

extern "C" void kernel_launch(void* const* d_in, const int* in_sizes, int n_in,
                              void* d_out, int out_size, void* d_ws, size_t ws_size,
                              hipStream_t stream) {
    const float* x   = (const float*)d_in[0];
    const float* Wa1 = (const float*)d_in[1];
    const float* ba1 = (const float*)d_in[2];
    const float* Wa2 = (const float*)d_in[3];
    const float* ba2 = (const float*)d_in[4];
    const float* Wb1 = (const float*)d_in[5];
    const float* bb1 = (const float*)d_in[6];
    const float* Wb2 = (const float*)d_in[7];
    const float* bb2 = (const float*)d_in[8];
    const float* lng = (const float*)d_in[9];
    const float* lnb = (const float*)d_in[10];
    const float* Wg  = (const float*)d_in[11];
    const float* bg  = (const float*)d_in[12];
    const float* Wz  = (const float*)d_in[13];
    const float* bz  = (const float*)d_in[14];
    float* out = (float*)d_out;
    char* ws = (char*)d_ws;
    u16*   a_ws = (u16*)(ws + OFF_A);
    u16*   b_ws = (u16*)(ws + OFF_B);
    float* z_ws = (float*)(ws + OFF_Z);
    u16*   g_ws = (u16*)(ws + OFF_G);
    u16*   wt   = (u16*)(ws + OFF_WT);
    float* bc   = (float*)(ws + OFF_BC);

    hipLaunchKernelGGL(pack_w, dim3(96), dim3(256), 0, stream,
                       Wa1, Wa2, Wb1, Wb2, Wg, ba1, ba2, bb1, bb2, bg, wt, bc);
    hipLaunchKernelGGL(proj_kernel, dim3(2048), dim3(512), 0, stream, x, wt, bc, a_ws, b_ws, g_ws);
    hipLaunchKernelGGL(tri_kernel, dim3(32, 16), dim3(512), 0, stream, a_ws, b_ws, z_ws);
    hipLaunchKernelGGL(out_kernel, dim3(1024), dim3(512), 0, stream, z_ws, g_ws, Wz, bz, lng, lnb, out);
}

// Round 11
// 308.171 us; speedup vs baseline: 1.0121x; 1.0121x over previous
//
#include <hip/hip_runtime.h>

// Triangle multiplication (outgoing), B=1 N=512 CZ=128 C=16, f32 I/O.
// BEST-KNOWN CONFIG (R9, 308.8us): K0 pack -> K1 proj (2048 blocks x 128 rows,
// W in LDS, direct-x A-frags, LDS-transpose epilogue) -> K2 tri (128x128 tile,
// fused scatter-transpose B staging + T14 async prefetch) -> K3 out (2-tile
// pipelined blocks, z prefetched).

#define NN 512
#define PP (NN*NN)        // 262144
#define CZD 128
#define CD 16
#define LN_EPS 1e-5f

typedef unsigned short u16;
typedef __bf16 bf16x8 __attribute__((ext_vector_type(8)));
typedef float  f32x4  __attribute__((ext_vector_type(4)));

// ws layout (bytes)
#define OFF_A  0u           // a planes: 16 x P x bf16 = 8 MB
#define OFF_B  8388608u     // b planes: 8 MB
#define OFF_Z  16777216u    // z: 16 x P x f32 = 16 MB
#define OFF_G  33554432u    // g: P x 128 x bf16 = 64 MB
#define OFF_WT 100663296u   // packed Wt[192][128] bf16
#define OFF_BC 100712448u   // bias cat [192] f32

__device__ __forceinline__ float bf2f(u16 u) {
    union { unsigned int i; float f; } v; v.i = ((unsigned int)u) << 16; return v.f;
}
// Native cast: compiler forms v_cvt_pk_bf16_f32 (RNE) from adjacent scalar casts.
__device__ __forceinline__ u16 f2bf(float f) {
    union { __bf16 b; u16 u; } v; v.b = (__bf16)f; return v.u;
}
__device__ __forceinline__ float sigmoidf(float x) { return 1.0f / (1.0f + __expf(-x)); }

// proj LDS addressing, 256B row stride. ROT-16 swizzle: granule' = (granule+row)&15.
__device__ __forceinline__ int swz(int row, int bytecol) {
    return row * 256 + ((((bytecol >> 4) + row) & 15) << 4) + (bytecol & 15);
}

// ---------------- K0: pack Wt[192][128] bf16 (row n holds W[:,n]) + bias[192] f32
__global__ void pack_w(const float* __restrict__ Wa1, const float* __restrict__ Wa2,
                       const float* __restrict__ Wb1, const float* __restrict__ Wb2,
                       const float* __restrict__ Wg,
                       const float* __restrict__ ba1, const float* __restrict__ ba2,
                       const float* __restrict__ bb1, const float* __restrict__ bb2,
                       const float* __restrict__ bg,
                       u16* __restrict__ wt, float* __restrict__ bc) {
    int idx = blockIdx.x * 256 + threadIdx.x;           // 0..24575
    int n = idx >> 7, k = idx & 127;
    float v;
    if      (n < 16) v = Wa1[k * CD + n];
    else if (n < 32) v = Wa2[k * CD + (n - 16)];
    else if (n < 48) v = Wb1[k * CD + (n - 32)];
    else if (n < 64) v = Wb2[k * CD + (n - 48)];
    else             v = Wg [k * CZD + (n - 64)];
    wt[n * CZD + k] = f2bf(v);
    if (idx < 192) {
        float b;
        if      (idx < 16) b = ba1[idx];
        else if (idx < 32) b = ba2[idx - 16];
        else if (idx < 48) b = bb1[idx - 32];
        else if (idx < 64) b = bb2[idx - 48];
        else               b = bg [idx - 64];
        bc[idx] = b;
    }
}

// ---------------- K1: X[P,128] @ Wcat[128,192] with fused sigmoid epilogue.
// R7-best config (frozen): 512 thr, 128 rows/block (2048 blocks), W in LDS 48KB,
// direct-x A-frags, LDS-transpose epilogue.
__global__ __launch_bounds__(512, 4) void proj_kernel(const float* __restrict__ x,
                                                      const u16* __restrict__ wt,
                                                      const float* __restrict__ bc,
                                                      u16* __restrict__ a_ws, u16* __restrict__ b_ws,
                                                      u16* __restrict__ g_ws) {
    __shared__ __align__(16) char lds[49152];           // W: 192 rows x 256B
    char* Wl = lds;
    char* aT = lds;                                     // epilogue reuse: 16 rows x 256B
    char* bT = lds + 4096;                              // 16 rows x 256B
    char* gT = lds + 8192;                              // 128 rows x 256B
    const int t = threadIdx.x;
    const int wv = t >> 6, lane = t & 63, l16 = lane & 15, quad = lane >> 4;
    const long pos0 = (long)blockIdx.x * 128;

    // issue A-fragment global loads first (8 x float4, in flight during W stage)
    const float* xrow = x + (pos0 + wv * 16 + l16) * CZD + quad * 8;
    float4 xa[4][2];
#pragma unroll
    for (int ks = 0; ks < 4; ++ks) {
        xa[ks][0] = *reinterpret_cast<const float4*>(xrow + ks * 32);
        xa[ks][1] = *reinterpret_cast<const float4*>(xrow + ks * 32 + 4);
    }

    // stage W: 192 rows x 16 granules(16B) = 3072 chunks, 6/thread
#pragma unroll
    for (int i = 0; i < 6; ++i) {
        int c = t + 512 * i;
        int n = c >> 4, g = c & 15;
        uint4 v = *reinterpret_cast<const uint4*>(wt + n * CZD + g * 8);
        *reinterpret_cast<uint4*>(Wl + swz(n, g * 16)) = v;
    }

    // convert A fragments f32 -> bf16 in registers
    bf16x8 af[4];
#pragma unroll
    for (int ks = 0; ks < 4; ++ks) {
        union { u16 s[8]; bf16x8 v; } tb;
        tb.s[0] = f2bf(xa[ks][0].x); tb.s[1] = f2bf(xa[ks][0].y);
        tb.s[2] = f2bf(xa[ks][0].z); tb.s[3] = f2bf(xa[ks][0].w);
        tb.s[4] = f2bf(xa[ks][1].x); tb.s[5] = f2bf(xa[ks][1].y);
        tb.s[6] = f2bf(xa[ks][1].z); tb.s[7] = f2bf(xa[ks][1].w);
        af[ks] = tb.v;
    }
    __syncthreads();

    f32x4 acc[12];
#pragma unroll
    for (int ct = 0; ct < 12; ++ct) acc[ct] = (f32x4){0.f, 0.f, 0.f, 0.f};
#pragma unroll
    for (int ks = 0; ks < 4; ++ks)
#pragma unroll
        for (int ct = 0; ct < 12; ++ct) {
            bf16x8 wb = *reinterpret_cast<const bf16x8*>(Wl + swz(ct * 16 + l16, ks * 64 + quad * 16));
            acc[ct] = __builtin_amdgcn_mfma_f32_16x16x32_bf16(af[ks], wb, acc[ct], 0, 0, 0);
        }
    __syncthreads();                                    // all waves done reading Wl

    // epilogue: sigmoid + transpose into LDS (aliases Wl region)
    {
        const float ba1 = bc[l16], ba2 = bc[16 + l16], bb1 = bc[32 + l16], bb2 = bc[48 + l16];
        u16 av[4], bv[4];
#pragma unroll
        for (int r = 0; r < 4; ++r) {
            av[r] = f2bf(sigmoidf((acc[0][r] + ba1) * (acc[1][r] + ba2)));
            bv[r] = f2bf(sigmoidf((acc[2][r] + bb1) * (acc[3][r] + bb2)));
        }
        *reinterpret_cast<uint2*>(aT + swz(l16, wv * 32 + quad * 8)) = *reinterpret_cast<const uint2*>(av);
        *reinterpret_cast<uint2*>(bT + swz(l16, wv * 32 + quad * 8)) = *reinterpret_cast<const uint2*>(bv);
#pragma unroll
        for (int ct = 0; ct < 8; ++ct) {
            const float bgv = bc[64 + ct * 16 + l16];
#pragma unroll
            for (int r = 0; r < 4; ++r) {
                int pos = wv * 16 + quad * 4 + r;
                *reinterpret_cast<u16*>(gT + swz(pos, ct * 32 + l16 * 2)) =
                    f2bf(sigmoidf(acc[4 + ct][r] + bgv));
            }
        }
    }
    __syncthreads();

    // coalesced write-out: aT/bT 4KB each (16 ch x 128 pos u16), gT 32KB
    if (t < 256) {
        int ch = t >> 4, i = t & 15;
        uint4 v = *reinterpret_cast<const uint4*>(aT + swz(ch, i * 16));
        *reinterpret_cast<uint4*>(a_ws + (long)ch * PP + pos0 + i * 8) = v;
    } else {
        int u = t - 256;
        int ch = u >> 4, i = u & 15;
        uint4 v = *reinterpret_cast<const uint4*>(bT + swz(ch, i * 16));
        *reinterpret_cast<uint4*>(b_ws + (long)ch * PP + pos0 + i * 8) = v;
    }
#pragma unroll
    for (int i = 0; i < 4; ++i) {
        int c = t + 512 * i;                             // 2048 = 128 pos x 16 granules
        int pos = c >> 4, g = c & 15;
        uint4 v = *reinterpret_cast<const uint4*>(gT + swz(pos, g * 16));
        *reinterpret_cast<uint4*>(g_ws + (pos0 + pos) * CZD + g * 8) = v;
    }
}

// ---------------- K2: per-channel Z_c = A_c @ B_c (512x512x512).
// R9-best (restored): 128x128 tile, BK=64, 512 threads, fused b32 scatter-
// transpose B staging + T14 async prefetch (next step's loads issued right
// after the stage barrier; latency hides under this step's ds_read+MFMA).
__global__ __launch_bounds__(512) void tri_kernel(const u16* __restrict__ a_ws,
                                                  const u16* __restrict__ b_ws,
                                                  float* __restrict__ z_ws) {
    __shared__ __align__(16) char Alds[16384];          // A: 128 rows x 128B, granule-swizzled
    __shared__ __align__(16) char Btl [16384];          // B^T: 128 j-rows x 128B (64 k), swizzled
    const int t = threadIdx.x;
    const int wv = t >> 6, lane = t & 63, l16 = lane & 15, quad = lane >> 4;
    const int wr = wv >> 2, wc = wv & 3;                // wave grid 2x4
    const int c = blockIdx.y;
    const int i0 = (blockIdx.x >> 2) * 128, j0 = (blockIdx.x & 3) * 128;
    const u16* Ap = a_ws + (long)c * PP;
    const u16* Bp = b_ws + (long)c * PP;

    // fixed per-thread staging coordinates
    const int ar0 = t >> 3,          ako0 = (t & 7) * 8;            // A chunk 0
    const int ar1 = (t + 512) >> 3,  ako1 = ((t + 512) & 7) * 8;    // A chunk 1
    const int bk  = (t >> 4) * 2,    bjo  = (t & 15) * 8;           // B k-pair
    const int bkg = bk >> 3,         bkl  = (bk & 7) * 2;

    f32x4 acc[4][2];
#pragma unroll
    for (int m = 0; m < 4; ++m)
#pragma unroll
        for (int n = 0; n < 2; ++n) acc[m][n] = (f32x4){0.f, 0.f, 0.f, 0.f};

    // prologue: issue k-step 0 loads
    uint4 aR0 = *reinterpret_cast<const uint4*>(Ap + (long)(i0 + ar0) * NN + ako0);
    uint4 aR1 = *reinterpret_cast<const uint4*>(Ap + (long)(i0 + ar1) * NN + ako1);
    uint4 bR0 = *reinterpret_cast<const uint4*>(Bp + (long)(bk)     * NN + j0 + bjo);
    uint4 bR1 = *reinterpret_cast<const uint4*>(Bp + (long)(bk + 1) * NN + j0 + bjo);

    for (int s = 0; s < 8; ++s) {
        // ds_write staged regs (waits on the in-flight loads)
        *reinterpret_cast<uint4*>(Alds + ar0 * 128 + ((ako0 * 2) ^ ((ar0 & 7) << 4))) = aR0;
        *reinterpret_cast<uint4*>(Alds + ar1 * 128 + ((ako1 * 2) ^ ((ar1 & 7) << 4))) = aR1;
        {
            union { uint4 v; u16 sh[8]; } t0, t1;
            t0.v = bR0; t1.v = bR1;
#pragma unroll
            for (int jj = 0; jj < 8; ++jj) {
                int j = bjo + jj;
                int gran = ((bkg ^ (j & 7)) + (j >> 3)) & 7;
                unsigned int pk = (unsigned int)t0.sh[jj] | ((unsigned int)t1.sh[jj] << 16);
                *reinterpret_cast<unsigned int*>(Btl + j * 128 + gran * 16 + bkl) = pk;
            }
        }
        __syncthreads();

        // issue NEXT step's loads now -- latency hides under this step's compute
        if (s < 7) {
            const int kn = (s + 1) * 64;
            aR0 = *reinterpret_cast<const uint4*>(Ap + (long)(i0 + ar0) * NN + kn + ako0);
            aR1 = *reinterpret_cast<const uint4*>(Ap + (long)(i0 + ar1) * NN + kn + ako1);
            bR0 = *reinterpret_cast<const uint4*>(Bp + (long)(kn + bk)     * NN + j0 + bjo);
            bR1 = *reinterpret_cast<const uint4*>(Bp + (long)(kn + bk + 1) * NN + j0 + bjo);
        }

#pragma unroll
        for (int ks = 0; ks < 2; ++ks) {                 // two K=32 halves
            bf16x8 af[4];
#pragma unroll
            for (int m = 0; m < 4; ++m) {
                int row = wr * 64 + m * 16 + l16;
                af[m] = *reinterpret_cast<const bf16x8*>(
                    Alds + row * 128 + ((ks * 64 + quad * 16) ^ ((row & 7) << 4)));
            }
#pragma unroll
            for (int n = 0; n < 2; ++n) {
                int jrow = wc * 32 + n * 16 + l16;
                int gran = (((ks * 4 + quad) ^ (jrow & 7)) + (jrow >> 3)) & 7;
                bf16x8 bf = *reinterpret_cast<const bf16x8*>(Btl + jrow * 128 + gran * 16);
#pragma unroll
                for (int m = 0; m < 4; ++m)
                    acc[m][n] = __builtin_amdgcn_mfma_f32_16x16x32_bf16(af[m], bf, acc[m][n], 0, 0, 0);
            }
        }
        __syncthreads();                                 // LDS free for next ds_write
    }
    float* Zp = z_ws + (long)c * PP;
#pragma unroll
    for (int m = 0; m < 4; ++m)
#pragma unroll
        for (int n = 0; n < 2; ++n)
#pragma unroll
            for (int r = 0; r < 4; ++r)
                Zp[(long)(i0 + wr * 64 + m * 16 + quad * 4 + r) * NN + j0 + wc * 32 + n * 16 + l16]
                    = acc[m][n][r];
}

// ---------------- K3: out[pos][cz] = g[pos][cz] * (LN(z[pos][:]) @ Wz + bz)[cz], f32 out
// (frozen) 1024 blocks x 2 tiles of 128 pos; z for both tiles loaded up-front.
__global__ __launch_bounds__(512) void out_kernel(const float* __restrict__ z_ws,
                                                  const u16* __restrict__ g_ws,
                                                  const float* __restrict__ Wz, const float* __restrict__ bz,
                                                  const float* __restrict__ lng, const float* __restrict__ lnb,
                                                  float* __restrict__ out) {
    __shared__ __align__(16) float zt[16][128];
    __shared__ __align__(16) float nl[128][20];          // 80B stride: 16B-aligned rows
    __shared__ __align__(16) float wzs[16][128];
    __shared__ float bzl[128];
    __shared__ float lg[16], lb[16];
    const int t = threadIdx.x;
    const long tbase = (long)blockIdx.x * 256;

    // up-front z loads for BOTH tiles (in flight during Wz stage + LN)
    const int zch = t >> 5, zoff = (t & 31) * 4;
    const float* zp = z_ws + (long)zch * PP + tbase + zoff;
    const float4 zv0 = *reinterpret_cast<const float4*>(zp);
    const float4 zv1 = *reinterpret_cast<const float4*>(zp + 128);

    {   // stage Wz: 2048 floats, 1 float4/thread
        int idx = t * 4;
        const float4 v = *reinterpret_cast<const float4*>(Wz + idx);
        *reinterpret_cast<float4*>(&wzs[idx >> 7][idx & 127]) = v;
    }
    if (t < 128)      bzl[t] = bz[t];
    else if (t < 144) lg[t - 128] = lng[t - 128];
    else if (t < 160) lb[t - 144] = lnb[t - 144];
    *reinterpret_cast<float4*>(&zt[zch][zoff]) = zv0;
    __syncthreads();

    // per-thread weight regs for the matvec (cz pair)
    const int czp = (t & 63) * 2, pg = t >> 6;
    float wzr[32];
#pragma unroll
    for (int c0 = 0; c0 < 16; ++c0) {
        wzr[2 * c0]     = wzs[c0][czp];
        wzr[2 * c0 + 1] = wzs[c0][czp + 1];
    }
    const float bz0 = bzl[czp], bz1 = bzl[czp + 1];
    const unsigned int* gp = reinterpret_cast<const unsigned int*>(g_ws);

#pragma unroll
    for (int it = 0; it < 2; ++it) {
        const long pos0 = tbase + it * 128;
        {   // LN over 16 channels; thread (p = t&127, cgr = t>>7) normalizes 4 channels
            int p = t & 127, cgr = t >> 7;
            float m = 0.f;
#pragma unroll
            for (int c0 = 0; c0 < 16; ++c0) m += zt[c0][p];
            m *= (1.f / 16.f);
            float v = 0.f;
#pragma unroll
            for (int c0 = 0; c0 < 16; ++c0) { float d = zt[c0][p] - m; v += d * d; }
            v *= (1.f / 16.f);
            float s = rsqrtf(v + LN_EPS);
#pragma unroll
            for (int cc = 0; cc < 4; ++cc) {
                int c0 = cgr * 4 + cc;
                nl[p][c0] = (zt[c0][p] - m) * s * lg[c0] + lb[c0];
            }
        }
        __syncthreads();                                 // nl ready; zt consumed
        if (it == 0)                                     // refill zt for tile 1 during matvec
            *reinterpret_cast<float4*>(&zt[zch][zoff]) = zv1;

        // matvec+gate: thread owns cz pair x 16 positions
#pragma unroll
        for (int pp2 = 0; pp2 < 16; ++pp2) {
            int p = pg * 16 + pp2;                       // wave-uniform -> nl reads broadcast
            const float4* np = reinterpret_cast<const float4*>(&nl[p][0]);
            float y0 = bz0, y1 = bz1;
#pragma unroll
            for (int c4 = 0; c4 < 4; ++c4) {
                float4 nv = np[c4];
                y0 += nv.x * wzr[(c4 * 4 + 0) * 2] + nv.y * wzr[(c4 * 4 + 1) * 2] +
                      nv.z * wzr[(c4 * 4 + 2) * 2] + nv.w * wzr[(c4 * 4 + 3) * 2];
                y1 += nv.x * wzr[(c4 * 4 + 0) * 2 + 1] + nv.y * wzr[(c4 * 4 + 1) * 2 + 1] +
                      nv.z * wzr[(c4 * 4 + 2) * 2 + 1] + nv.w * wzr[(c4 * 4 + 3) * 2 + 1];
            }
            long o = (pos0 + p) * CZD + czp;
            unsigned int gg = gp[o >> 1];                // o even: czp even, CZD even
            float g0 = bf2f((u16)(gg & 0xffffu));
            float g1 = bf2f((u16)(gg >> 16));
            float2 res; res.x = g0 * y0; res.y = g1 * y1;
            *reinterpret_cast<float2*>(out + o) = res;
        }
        __syncthreads();                                 // zt(1) visible, nl free
    }
}

extern "C" void kernel_launch(void* const* d_in, const int* in_sizes, int n_in,
                              void* d_out, int out_size, void* d_ws, size_t ws_size,
                              hipStream_t stream) {
    const float* x   = (const float*)d_in[0];
    const float* Wa1 = (const float*)d_in[1];
    const float* ba1 = (const float*)d_in[2];
    const float* Wa2 = (const float*)d_in[3];
    const float* ba2 = (const float*)d_in[4];
    const float* Wb1 = (const float*)d_in[5];
    const float* bb1 = (const float*)d_in[6];
    const float* Wb2 = (const float*)d_in[7];
    const float* bb2 = (const float*)d_in[8];
    const float* lng = (const float*)d_in[9];
    const float* lnb = (const float*)d_in[10];
    const float* Wg  = (const float*)d_in[11];
    const float* bg  = (const float*)d_in[12];
    const float* Wz  = (const float*)d_in[13];
    const float* bz  = (const float*)d_in[14];
    float* out = (float*)d_out;
    char* ws = (char*)d_ws;
    u16*   a_ws = (u16*)(ws + OFF_A);
    u16*   b_ws = (u16*)(ws + OFF_B);
    float* z_ws = (float*)(ws + OFF_Z);
    u16*   g_ws = (u16*)(ws + OFF_G);
    u16*   wt   = (u16*)(ws + OFF_WT);
    float* bc   = (float*)(ws + OFF_BC);

    hipLaunchKernelGGL(pack_w, dim3(96), dim3(256), 0, stream,
                       Wa1, Wa2, Wb1, Wb2, Wg, ba1, ba2, bb1, bb2, bg, wt, bc);
    hipLaunchKernelGGL(proj_kernel, dim3(2048), dim3(512), 0, stream, x, wt, bc, a_ws, b_ws, g_ws);
    hipLaunchKernelGGL(tri_kernel, dim3(16, 16), dim3(512), 0, stream, a_ws, b_ws, z_ws);
    hipLaunchKernelGGL(out_kernel, dim3(1024), dim3(512), 0, stream, z_ws, g_ws, Wz, bz, lng, lnb, out);
}